// Round 20
// baseline (125.076 us; speedup 1.0000x reference)
//
#include <hip/hip_runtime.h>
#include <hip/hip_bf16.h>

// Problem constants (from reference)
constexpr int T_ = 4;
constexpr int B_ = 8;
constexpr int N_ = 5000;
constexpr int E_ = 80000;
constexpr int TBN = T_ * B_ * N_;   // 160000
constexpr int NXCD = 8;
constexpr int CAP = 64;             // bucket-CSR capacity per node

// layer-kernel geometry: 8 lanes per node (4 edge-stripes x 2 feature-halves),
// 32 nodes per 256-thread block
constexpr int NPB = 32;
constexpr int CH  = (N_ + NPB - 1) / NPB;     // 157 chunks per graph
constexpr int GRP = T_ * B_ / NXCD;           // 4 graphs per XCD
constexpr int LB  = NXCD * CH * GRP;          // 5024 blocks
constexpr int EB  = (E_ + 255) / 256;         // 313 scatter blocks
constexpr int IB  = TBN / 256;                // 625 init blocks

// record: 48B = uint4 x3 per node: [0][1] gs fp16 x16; [2] {x,y,z,charge}

// packed fp16 helpers
typedef _Float16 h2 __attribute__((ext_vector_type(2)));
__device__ __forceinline__ unsigned h2u(h2 v) {
    union { h2 h; unsigned u; } x; x.h = v; return x.u;
}
__device__ __forceinline__ h2 u2h(unsigned u) {
    union { h2 h; unsigned u; } x; x.u = u; return x.h;
}
__device__ __forceinline__ unsigned f16pack2(float lo, float hi) {
    auto v = __builtin_amdgcn_cvt_pkrtz(lo, hi);   // __fp16 ext_vector(2)
    union { decltype(v) h; unsigned u; } x; x.h = v; return x.u;
}
__device__ __forceinline__ void f16unpack2(unsigned u, float& lo, float& hi) {
    h2 v = u2h(u); lo = (float)v[0]; hi = (float)v[1];
}

// ---------------------------------------------------------------------------
// Fused: bucket-CSR scatter (blocks < EB) || record xyz+charge / vec init /
// out zeroing (blocks >= EB).
// ---------------------------------------------------------------------------
__global__ void k_build(const int* __restrict__ src, const int* __restrict__ dst,
                        int* __restrict__ cursor, unsigned short* __restrict__ csr_b,
                        const float* __restrict__ xs, const float* __restrict__ vs,
                        const float* __restrict__ charges,
                        float4* __restrict__ rec0, float4* __restrict__ rec1,
                        float* __restrict__ vec, float4* __restrict__ outz) {
    const int bid = blockIdx.x;
    const int tid = threadIdx.x;
    if (bid < EB) {
        int e = bid * 256 + tid;
        if (e < E_) {
            int d = dst[e];
            int pos = atomicAdd(&cursor[d], 1);
            if (pos < CAP) csr_b[d * CAP + pos] = (unsigned short)src[e];
        }
    } else {
        int g = (bid - EB) * 256 + tid;    // exact: IB*256 == TBN
        int tb = g / N_;
        int n  = g - tb * N_;
        int b  = tb % B_;
        float c = charges[b * N_ + n];
        float4 xc = make_float4(xs[3*(size_t)g], xs[3*(size_t)g+1], xs[3*(size_t)g+2], c);
        rec0[(size_t)g * 3 + 2] = xc;
        rec1[(size_t)g * 3 + 2] = xc;
        vec[3*(size_t)g+0] = vs[3*(size_t)g+0];
        vec[3*(size_t)g+1] = vs[3*(size_t)g+1];
        vec[3*(size_t)g+2] = vs[3*(size_t)g+2];
        if (g < (B_ * N_ * 3) / 4) outz[g] = make_float4(0.f, 0.f, 0.f, 0.f);
    }
}

// ---------------------------------------------------------------------------
// Fused layer kernel — 8 lanes/node (4 edge-stripes x 2 feature-halves).
// CHAIN-FREE edge loop: stripe pr owns the CONTIGUOUS bucket slice
// [pr*q, pr*q+q), q=ceil(deg/4). All q<=8 csr indices are loaded upfront as
// independent coalesced ushort loads, then a fully-unrolled 8-step loop whose
// gathers have no load->load dependence (compiler hoists freely). Phantom
// steps masked by packed multiply; index clamped (garbage slots safe).
// Rare deg>32 handled by a scalar tail. gs/gd/h fp16, edge MLP packed fp16.
// LYR==0: gs0[s]=c_s*P, gd0=c_n*Q+b1 inline (charge in rec.w).
// HAS_NEXT tail: 2-features-per-lane hnew/gs/gd + octet shfl exchange.
// !HAS_NEXT: atomic-accumulate softmax(theta)[t]*(vec+av+x) into out.
// ---------------------------------------------------------------------------
template <int LYR, bool HAS_NEXT>
__global__ __launch_bounds__(256, 6) void k_layer(
        const float4* __restrict__ rec_in, float4* __restrict__ rec_out,
        const float* __restrict__ W_embed,
        const float* __restrict__ W1, const float* __restrict__ b1,
        const float* __restrict__ W2, const float* __restrict__ b2,
        const float* __restrict__ Wv, const float* __restrict__ theta,
        const int* __restrict__ degv, const unsigned short* __restrict__ csr_b,
        unsigned* __restrict__ hbuf, unsigned* __restrict__ gd,
        float* __restrict__ vec, float* __restrict__ outp) {
    __shared__ float s_w1e[16], s_wv[16], s_b2[16], s_b1[16], s_b1n[16];
    __shared__ float s_W2[256];
    __shared__ float s_W1sn[256];
    __shared__ float s_W1dn[256];
    __shared__ float s_P[16], s_Q[16], s_rwe[16];
    const int tid = threadIdx.x;
    if (tid < 16) {
        s_w1e[tid] = W1[LYR * 528 + 512 + tid];
        s_wv[tid]  = Wv[LYR * 16 + tid];
        s_b2[tid]  = b2[LYR * 16 + tid];
        s_b1[tid]  = b1[LYR * 16 + tid];
        if (HAS_NEXT) s_b1n[tid] = b1[(LYR + 1) * 16 + tid];
    }
    s_W2[tid] = W2[LYR * 256 + tid];
    if (HAS_NEXT) {
        s_W1sn[tid] = W1[(LYR + 1) * 528 + tid];
        s_W1dn[tid] = W1[(LYR + 1) * 528 + 256 + tid];
    }
    if (LYR == 0 && tid < 16) {
        float accP = 0.0f, accQ = 0.0f;
        for (int j = 0; j < 16; ++j) {
            float r = fmaxf(W_embed[j], 0.0f);
            accP += r * W1[j * 16 + tid];
            accQ += r * W1[256 + j * 16 + tid];
        }
        s_P[tid] = accP; s_Q[tid] = accQ;
        s_rwe[tid] = fmaxf(W_embed[tid], 0.0f);
    }
    __syncthreads();

    // XCD swizzle bijection over 5024 = 8 * 628 blocks (628 = 157 * 4)
    const int bid   = blockIdx.x;
    const int xcd   = bid & 7;
    const int j     = bid >> 3;            // 0..627
    const int tb    = xcd + NXCD * (j / CH);
    const int chunk = j % CH;
    const int o     = tid & 7;             // octet lane
    const int node  = chunk * NPB + (tid >> 3);
    const int half  = o & 1;               // feature half (0: f0-7, 1: f8-15)
    const int pr    = o >> 1;              // edge stripe 0..3
    const int hb    = half * 8;            // own feature base
    if (node >= N_) return;                // whole octet exits together

    const int g = tb * N_ + node;
    const size_t nb = (size_t)tb * N_;
    const uint4* r4 = (const uint4*)rec_in;

    // softmax weight for own t (final layer only)
    float wsm = 0.0f;
    if (!HAS_NEXT) {
        float t0 = theta[0], t1 = theta[1], t2 = theta[2], t3 = theta[3];
        float mx = fmaxf(fmaxf(t0, t1), fmaxf(t2, t3));
        float e0 = expf(t0 - mx), e1 = expf(t1 - mx);
        float e2 = expf(t2 - mx), e3 = expf(t3 - mx);
        float inv = 1.0f / (e0 + e1 + e2 + e3);
        int tt = tb >> 3;                  // tb = t*8 + b
        wsm = ((tt == 0) ? e0 : (tt == 1) ? e1 : (tt == 2) ? e2 : e3) * inv;
    }

    const float4 xn = rec_in[(size_t)g * 3 + 2];
    const float c0 = xn.w;

    // packed per-half weights (from f32 LDS, once per thread)
    h2 w1e_pk[4], wv_pk[4], P_pk[4];
#pragma unroll
    for (int k = 0; k < 4; ++k) {
        w1e_pk[k] = u2h(f16pack2(s_w1e[hb + 2*k], s_w1e[hb + 2*k + 1]));
        wv_pk[k]  = u2h(f16pack2(s_wv[hb + 2*k],  s_wv[hb + 2*k + 1]));
        if (LYR == 0) P_pk[k] = u2h(f16pack2(s_P[hb + 2*k], s_P[hb + 2*k + 1]));
    }

    // gdn: own 8-feature half, packed
    h2 gdn_pk[4];
    if (LYR == 0) {
#pragma unroll
        for (int k = 0; k < 4; ++k)
            gdn_pk[k] = u2h(f16pack2(c0 * s_Q[hb + 2*k]     + s_b1[hb + 2*k],
                                     c0 * s_Q[hb + 2*k + 1] + s_b1[hb + 2*k + 1]));
    } else {
        uint4 da = ((const uint4*)gd)[(size_t)g * 2 + half];
        gdn_pk[0] = u2h(da.x); gdn_pk[1] = u2h(da.y);
        gdn_pk[2] = u2h(da.z); gdn_pk[3] = u2h(da.w);
    }

    const h2 h2z = {(_Float16)0.0f, (_Float16)0.0f};
    h2 agg_pk[4] = {h2z, h2z, h2z, h2z};
    float av0 = 0.0f, av1 = 0.0f, av2 = 0.0f;

    const int deg = min(degv[node], CAP);
    const int rs = node * CAP;

    // contiguous stripe: [my0, my0+myn) of this node's bucket
    const int q   = (deg + 3) >> 2;        // <= 16
    const int my0 = pr * q;
    const int myn = max(0, min(q, deg - my0));

    // edge MLP body (mk = 1 real, 0 phantom)
    auto edge = [&](const float4& xc, const uint4& ga, float mk) {
        float d0 = xn.x - xc.x;
        float d1 = xn.y - xc.y;
        float d2v = xn.z - xc.z;
        float dd = d0*d0 + d1*d1 + d2v*d2v;
        _Float16 ddh = (_Float16)dd;
        h2 dd2 = {ddh, ddh};
        h2 cs2 = h2z;
        if (LYR == 0) { _Float16 ch = (_Float16)xc.w; cs2 = (h2){ch, ch}; }
        _Float16 mh = (_Float16)mk;
        h2 mk2 = {mh, mh};

        h2 sv = h2z;
#pragma unroll
        for (int k = 0; k < 4; ++k) {
            h2 gsk;
            if (LYR == 0) gsk = cs2 * P_pk[k];
            else gsk = u2h(k == 0 ? ga.x : (k == 1 ? ga.y : (k == 2 ? ga.z : ga.w)));
            h2 m = dd2 * w1e_pk[k] + gdn_pk[k] + gsk;
            m = __builtin_elementwise_max(m, h2z);
            m = m * mk2;
            if (HAS_NEXT) agg_pk[k] += m;
            sv = m * wv_pk[k] + sv;
        }
        float sval = (float)sv[0] + (float)sv[1];
        sval += __shfl_xor(sval, 1);       // combine halves (pair-uniform)
        av0 = __builtin_fmaf(d0, sval, av0);
        av1 = __builtin_fmaf(d1, sval, av1);
        av2 = __builtin_fmaf(d2v, sval, av2);
    };

    // ---- chain-free 8-step edge phase (covers q <= 8, i.e. deg <= 32) ----
    {
        const int kn = min(myn, 8);
        // independent coalesced index loads (clamped to stay in-bucket; the
        // bucket has CAP=64 slots, my0+7 <= 3*16+7 < 64)
        int s0 = min((int)csr_b[rs + my0 + 0], N_ - 1);
        int s1 = min((int)csr_b[rs + my0 + 1], N_ - 1);
        int s2 = min((int)csr_b[rs + my0 + 2], N_ - 1);
        int s3 = min((int)csr_b[rs + my0 + 3], N_ - 1);
        int s4 = min((int)csr_b[rs + my0 + 4], N_ - 1);
        int s5 = min((int)csr_b[rs + my0 + 5], N_ - 1);
        int s6 = min((int)csr_b[rs + my0 + 6], N_ - 1);
        int s7 = min((int)csr_b[rs + my0 + 7], N_ - 1);
        int sx[8] = {s0, s1, s2, s3, s4, s5, s6, s7};
#pragma unroll
        for (int k = 0; k < 8; ++k) {
            size_t si = nb + (size_t)sx[k];
            float4 xc = rec_in[si * 3 + 2];
            uint4  ga = {0, 0, 0, 0};
            if (LYR != 0) ga = r4[si * 3 + half];
            edge(xc, ga, (k < kn) ? 1.0f : 0.0f);
        }
    }
    // rare tail: deg > 32 (q > 8)
    if (myn > 8) {
        for (int k = 8; k < myn; ++k) {
            int s = min((int)csr_b[rs + my0 + k], N_ - 1);
            size_t si = nb + (size_t)s;
            float4 xc = rec_in[si * 3 + 2];
            uint4  ga = {0, 0, 0, 0};
            if (LYR != 0) ga = r4[si * 3 + half];
            edge(xc, ga, 1.0f);
        }
    }

    // av reduce across the 4 pairs (pair lanes already identical)
    av0 += __shfl_xor(av0, 2); av0 += __shfl_xor(av0, 4);
    av1 += __shfl_xor(av1, 2); av1 += __shfl_xor(av1, 4);
    av2 += __shfl_xor(av2, 2); av2 += __shfl_xor(av2, 4);

    if (HAS_NEXT) {
        if (o < 3) {
            float myav = (o == 0) ? av0 : ((o == 1) ? av1 : av2);
            vec[(size_t)g * 3 + o] += myav;    // vec pre-initialized to vs
        }

        // full agg for own half: packed reduce across pairs, then unpack + partner
        float agg[8], aggO[8];
#pragma unroll
        for (int k = 0; k < 4; ++k) {
            agg_pk[k] += u2h(__shfl_xor(h2u(agg_pk[k]), 2));
            agg_pk[k] += u2h(__shfl_xor(h2u(agg_pk[k]), 4));
            unsigned po = __shfl_xor(h2u(agg_pk[k]), 1);
            h2 v = agg_pk[k], vo = u2h(po);
            agg[2*k]   = (float)v[0];  agg[2*k+1]  = (float)v[1];
            aggO[2*k]  = (float)vo[0]; aggO[2*k+1] = (float)vo[1];
        }
        const int j0 = hb;          // W2 row base for own-half agg
        const int j1 = 8 - hb;      // row base for partner-half agg

        // hn: own 2 features (columns o*2, o*2+1), fp16 in hbuf
        float hq0, hq1;
        if (LYR == 0) {
            hq0 = c0 * s_rwe[o * 2];
            hq1 = c0 * s_rwe[o * 2 + 1];
        } else {
            f16unpack2(hbuf[(size_t)g * 8 + o], hq0, hq1);
        }

        float a0 = s_b2[o * 2], a1 = s_b2[o * 2 + 1];
#pragma unroll
        for (int k = 0; k < 8; ++k) {
            a0 = __builtin_fmaf(agg[k],  s_W2[(j0 + k) * 16 + o * 2],     a0);
            a1 = __builtin_fmaf(agg[k],  s_W2[(j0 + k) * 16 + o * 2 + 1], a1);
            a0 = __builtin_fmaf(aggO[k], s_W2[(j1 + k) * 16 + o * 2],     a0);
            a1 = __builtin_fmaf(aggO[k], s_W2[(j1 + k) * 16 + o * 2 + 1], a1);
        }
        hq0 += fmaxf(a0, 0.0f);
        hq1 += fmaxf(a1, 0.0f);

        // exchange across the octet -> full hnew[16]
        const int lane = tid & 63;
        const int lbase = lane & ~7;
        float hfull[16];
#pragma unroll
        for (int sq = 0; sq < 8; ++sq) {
            hfull[sq * 2]     = __shfl(hq0, lbase + sq, 64);
            hfull[sq * 2 + 1] = __shfl(hq1, lbase + sq, 64);
        }

        // next-layer projections, own 2 columns
        float gs0 = 0.0f, gs1 = 0.0f;
        float gd0 = s_b1n[o * 2], gd1 = s_b1n[o * 2 + 1];
#pragma unroll
        for (int jj = 0; jj < 16; ++jj) {
            float hj = hfull[jj];
            gs0 = __builtin_fmaf(hj, s_W1sn[jj * 16 + o * 2],     gs0);
            gs1 = __builtin_fmaf(hj, s_W1sn[jj * 16 + o * 2 + 1], gs1);
            gd0 = __builtin_fmaf(hj, s_W1dn[jj * 16 + o * 2],     gd0);
            gd1 = __builtin_fmaf(hj, s_W1dn[jj * 16 + o * 2 + 1], gd1);
        }

        hbuf[(size_t)g * 8 + o] = f16pack2(hq0, hq1);
        // gs pair -> rec_out uint index g*12 + o (record = 12 uints, gs = 0..7)
        ((unsigned*)rec_out)[(size_t)g * 12 + o] = f16pack2(gs0, gs1);
        ((unsigned*)gd)[(size_t)g * 8 + o]       = f16pack2(gd0, gd1);
    } else {
        // final layer: out[b*N+node] += w_t * (vec + av + x)
        if (o < 3) {
            float myav = (o == 0) ? av0 : ((o == 1) ? av1 : av2);
            float xno  = (o == 0) ? xn.x : ((o == 1) ? xn.y : xn.z);
            float prev = vec[(size_t)g * 3 + o];
            int b = tb & 7;
            atomicAdd(&outp[((size_t)b * N_ + node) * 3 + o],
                      wsm * (prev + myav + xno));
        }
    }
}

// ---------------------------------------------------------------------------
extern "C" void kernel_launch(void* const* d_in, const int* in_sizes, int n_in,
                              void* d_out, int out_size, void* d_ws, size_t ws_size,
                              hipStream_t stream) {
    const float* xs       = (const float*)d_in[0];
    const float* vs       = (const float*)d_in[1];
    const float* charges  = (const float*)d_in[2];
    const int*   edge_src = (const int*)d_in[3];
    const int*   edge_dst = (const int*)d_in[4];
    const float* theta    = (const float*)d_in[5];
    const float* W_embed  = (const float*)d_in[6];
    const float* W1       = (const float*)d_in[7];
    const float* b1       = (const float*)d_in[8];
    const float* W2       = (const float*)d_in[9];
    const float* b2       = (const float*)d_in[10];
    const float* Wv       = (const float*)d_in[11];
    float* out = (float*)d_out;

    // workspace layout (256B aligned)
    char* w = (char*)d_ws;
    size_t off = 0;
    auto take = [&](size_t bytes) {
        size_t o = off;
        off = (off + bytes + 255) & ~(size_t)255;
        return o;
    };
    int*            cursor = (int*)(w + take((size_t)N_ * 4));
    unsigned short* csr_b  = (unsigned short*)(w + take((size_t)N_ * CAP * 2));
    float4*         rec0   = (float4*)(w + take((size_t)TBN * 48));
    float4*         rec1   = (float4*)(w + take((size_t)TBN * 48));
    unsigned*       hbuf   = (unsigned*)(w + take((size_t)TBN * 32));   // fp16 x16
    unsigned*       gd     = (unsigned*)(w + take((size_t)TBN * 32));
    float*          vec    = (float*)(w + take((size_t)TBN * 3 * 4));
    (void)ws_size;

    hipMemsetAsync(cursor, 0, (size_t)N_ * 4, stream);
    k_build<<<EB + IB, 256, 0, stream>>>(edge_src, edge_dst, cursor, csr_b,
                                         xs, vs, charges, rec0, rec1, vec,
                                         (float4*)out);

    // layer 0 reads rec0 (xyz+charge), writes rec1.gs + gd + h; layer 1 reads
    // rec1, writes rec0.gs + gd + h; layer 2 reads rec0, accumulates out
    k_layer<0, true ><<<LB, 256, 0, stream>>>(rec0, rec1, W_embed, W1, b1, W2, b2, Wv,
                                              theta, cursor, csr_b, hbuf, gd, vec, out);
    k_layer<1, true ><<<LB, 256, 0, stream>>>(rec1, rec0, W_embed, W1, b1, W2, b2, Wv,
                                              theta, cursor, csr_b, hbuf, gd, vec, out);
    k_layer<2, false><<<LB, 256, 0, stream>>>(rec0, nullptr, W_embed, W1, b1, W2, b2, Wv,
                                              theta, cursor, csr_b, hbuf, gd, vec, out);
}

// Round 21
// 100.125 us; speedup vs baseline: 1.2492x; 1.2492x over previous
//
#include <hip/hip_runtime.h>
#include <hip/hip_bf16.h>

// Problem constants (from reference)
constexpr int T_ = 4;
constexpr int B_ = 8;
constexpr int N_ = 5000;
constexpr int E_ = 80000;
constexpr int TBN = T_ * B_ * N_;   // 160000
constexpr int NXCD = 8;
constexpr int CAP = 64;             // bucket-CSR capacity per node (max deg << 64)

// layer-kernel geometry: 8 lanes per node (4 edge-stripes x 2 feature-halves),
// 32 nodes per 256-thread block
constexpr int NPB = 32;
constexpr int CH  = (N_ + NPB - 1) / NPB;     // 157 chunks per graph
constexpr int GRP = T_ * B_ / NXCD;           // 4 graphs per XCD
constexpr int LB  = NXCD * CH * GRP;          // 5024 blocks
constexpr int EB  = (E_ + 255) / 256;         // 313 scatter blocks
constexpr int IB  = TBN / 256;                // 625 init blocks

// record: 48B = uint4 x3 per node: [0][1] gs fp16 x16; [2] {x,y,z,charge}

// packed fp16 helpers
typedef _Float16 h2 __attribute__((ext_vector_type(2)));
__device__ __forceinline__ unsigned h2u(h2 v) {
    union { h2 h; unsigned u; } x; x.h = v; return x.u;
}
__device__ __forceinline__ h2 u2h(unsigned u) {
    union { h2 h; unsigned u; } x; x.u = u; return x.h;
}
__device__ __forceinline__ unsigned f16pack2(float lo, float hi) {
    auto v = __builtin_amdgcn_cvt_pkrtz(lo, hi);   // __fp16 ext_vector(2)
    union { decltype(v) h; unsigned u; } x; x.h = v; return x.u;
}
__device__ __forceinline__ void f16unpack2(unsigned u, float& lo, float& hi) {
    h2 v = u2h(u); lo = (float)v[0]; hi = (float)v[1];
}

// ---------------------------------------------------------------------------
// Fused: bucket-CSR scatter (blocks < EB) || record xyz+charge / vec init.
// ---------------------------------------------------------------------------
__global__ void k_build(const int* __restrict__ src, const int* __restrict__ dst,
                        int* __restrict__ cursor, unsigned short* __restrict__ csr_b,
                        const float* __restrict__ xs, const float* __restrict__ vs,
                        const float* __restrict__ charges,
                        float4* __restrict__ rec0, float4* __restrict__ rec1,
                        float* __restrict__ vec) {
    const int bid = blockIdx.x;
    const int tid = threadIdx.x;
    if (bid < EB) {
        int e = bid * 256 + tid;
        if (e < E_) {
            int d = dst[e];
            int pos = atomicAdd(&cursor[d], 1);
            if (pos < CAP) csr_b[d * CAP + pos] = (unsigned short)src[e];
        }
    } else {
        int g = (bid - EB) * 256 + tid;    // exact: IB*256 == TBN
        int tb = g / N_;
        int n  = g - tb * N_;
        int b  = tb % B_;
        float c = charges[b * N_ + n];
        float4 xc = make_float4(xs[3*(size_t)g], xs[3*(size_t)g+1], xs[3*(size_t)g+2], c);
        rec0[(size_t)g * 3 + 2] = xc;
        rec1[(size_t)g * 3 + 2] = xc;
        vec[3*(size_t)g+0] = vs[3*(size_t)g+0];
        vec[3*(size_t)g+1] = vs[3*(size_t)g+1];
        vec[3*(size_t)g+2] = vs[3*(size_t)g+2];
    }
}

// ---------------------------------------------------------------------------
// Fused layer kernel — 8 lanes/node (4 edge-stripes x 2 feature-halves),
// depth-2 pipelined gathers, bucket CSR (ushort), gs/gd/h stored fp16.
// Edge MLP in PACKED fp16 (v_pk_fma/v_pk_add/v_pk_max). This is the measured
// plateau config (100.2 us): waves=24/CU via (256,6); deeper ILP, more waves,
// fewer-VALU and chain-free variants all individually neutral or worse
// (R18/R19/R20) — the layers sit at the scattered-request TA/L2 throughput
// floor for this gather pattern.
// LYR==0: gs0[s]=c_s*P (packed), gd0=c_n*Q+b1 inline (charge in rec.w).
// HAS_NEXT tail: 2-features-per-lane hnew/gs/gd + octet shfl exchange (f32).
// !HAS_NEXT: atomic-accumulate softmax(theta)[t]*(vec+av+x) into out.
// ---------------------------------------------------------------------------
template <int LYR, bool HAS_NEXT>
__global__ __launch_bounds__(256, 6) void k_layer(
        const float4* __restrict__ rec_in, float4* __restrict__ rec_out,
        const float* __restrict__ W_embed,
        const float* __restrict__ W1, const float* __restrict__ b1,
        const float* __restrict__ W2, const float* __restrict__ b2,
        const float* __restrict__ Wv, const float* __restrict__ theta,
        const int* __restrict__ degv, const unsigned short* __restrict__ csr_b,
        unsigned* __restrict__ hbuf, unsigned* __restrict__ gd,
        float* __restrict__ vec, float* __restrict__ outp) {
    __shared__ float s_w1e[16], s_wv[16], s_b2[16], s_b1[16], s_b1n[16];
    __shared__ float s_W2[256];
    __shared__ float s_W1sn[256];
    __shared__ float s_W1dn[256];
    __shared__ float s_P[16], s_Q[16], s_rwe[16];
    const int tid = threadIdx.x;
    if (tid < 16) {
        s_w1e[tid] = W1[LYR * 528 + 512 + tid];
        s_wv[tid]  = Wv[LYR * 16 + tid];
        s_b2[tid]  = b2[LYR * 16 + tid];
        s_b1[tid]  = b1[LYR * 16 + tid];
        if (HAS_NEXT) s_b1n[tid] = b1[(LYR + 1) * 16 + tid];
    }
    s_W2[tid] = W2[LYR * 256 + tid];
    if (HAS_NEXT) {
        s_W1sn[tid] = W1[(LYR + 1) * 528 + tid];
        s_W1dn[tid] = W1[(LYR + 1) * 528 + 256 + tid];
    }
    if (LYR == 0 && tid < 16) {
        float accP = 0.0f, accQ = 0.0f;
        for (int j = 0; j < 16; ++j) {
            float r = fmaxf(W_embed[j], 0.0f);
            accP += r * W1[j * 16 + tid];
            accQ += r * W1[256 + j * 16 + tid];
        }
        s_P[tid] = accP; s_Q[tid] = accQ;
        s_rwe[tid] = fmaxf(W_embed[tid], 0.0f);
    }
    __syncthreads();

    // XCD swizzle bijection over 5024 = 8 * 628 blocks (628 = 157 * 4)
    const int bid   = blockIdx.x;
    const int xcd   = bid & 7;
    const int j     = bid >> 3;            // 0..627
    const int tb    = xcd + NXCD * (j / CH);
    const int chunk = j % CH;
    const int o     = tid & 7;             // octet lane
    const int node  = chunk * NPB + (tid >> 3);
    const int half  = o & 1;               // feature half (0: f0-7, 1: f8-15)
    const int pr    = o >> 1;              // edge stripe 0..3
    const int hb    = half * 8;            // own feature base
    if (node >= N_) return;                // whole octet exits together

    const int g = tb * N_ + node;
    const size_t nb = (size_t)tb * N_;
    const uint4* r4 = (const uint4*)rec_in;

    // softmax weight for own t (final layer only)
    float wsm = 0.0f;
    if (!HAS_NEXT) {
        float t0 = theta[0], t1 = theta[1], t2 = theta[2], t3 = theta[3];
        float mx = fmaxf(fmaxf(t0, t1), fmaxf(t2, t3));
        float e0 = expf(t0 - mx), e1 = expf(t1 - mx);
        float e2 = expf(t2 - mx), e3 = expf(t3 - mx);
        float inv = 1.0f / (e0 + e1 + e2 + e3);
        int tt = tb >> 3;                  // tb = t*8 + b
        wsm = ((tt == 0) ? e0 : (tt == 1) ? e1 : (tt == 2) ? e2 : e3) * inv;
    }

    const float4 xn = rec_in[(size_t)g * 3 + 2];
    const float c0 = xn.w;

    // packed per-half weights (from f32 LDS, once per thread)
    h2 w1e_pk[4], wv_pk[4], P_pk[4];
#pragma unroll
    for (int k = 0; k < 4; ++k) {
        w1e_pk[k] = u2h(f16pack2(s_w1e[hb + 2*k], s_w1e[hb + 2*k + 1]));
        wv_pk[k]  = u2h(f16pack2(s_wv[hb + 2*k],  s_wv[hb + 2*k + 1]));
        if (LYR == 0) P_pk[k] = u2h(f16pack2(s_P[hb + 2*k], s_P[hb + 2*k + 1]));
    }

    // gdn: own 8-feature half, packed
    h2 gdn_pk[4];
    if (LYR == 0) {
#pragma unroll
        for (int k = 0; k < 4; ++k)
            gdn_pk[k] = u2h(f16pack2(c0 * s_Q[hb + 2*k]     + s_b1[hb + 2*k],
                                     c0 * s_Q[hb + 2*k + 1] + s_b1[hb + 2*k + 1]));
    } else {
        uint4 da = ((const uint4*)gd)[(size_t)g * 2 + half];
        gdn_pk[0] = u2h(da.x); gdn_pk[1] = u2h(da.y);
        gdn_pk[2] = u2h(da.z); gdn_pk[3] = u2h(da.w);
    }

    const h2 h2z = {(_Float16)0.0f, (_Float16)0.0f};
    h2 agg_pk[4] = {h2z, h2z, h2z, h2z};
    float av0 = 0.0f, av1 = 0.0f, av2 = 0.0f;

    const int deg = min(degv[node], CAP);
    const int rs = node * CAP;
    const int re = rs + deg;

    // ---- depth-2 pipelined edge loop (edges striped across the 4 pairs) ----
    int e = rs + pr;
    bool have = e < re;
    int s = have ? (int)csr_b[e] : 0;
    size_t si = nb + (size_t)s;
    float4 xc = rec_in[si * 3 + 2];
    uint4  ga;
    if (LYR != 0) ga = r4[si * 3 + half];

    while (have) {
        // prefetch next edge (stride 4)
        int e2 = e + 4;
        bool have2 = e2 < re;
        int s2 = have2 ? (int)csr_b[e2] : 0;
        size_t si2 = nb + (size_t)s2;
        float4 xc2 = rec_in[si2 * 3 + 2];
        uint4  ga2;
        if (LYR != 0) ga2 = r4[si2 * 3 + half];

        // compute current edge (own feature half), packed fp16
        float d0 = xn.x - xc.x;
        float d1 = xn.y - xc.y;
        float d2v = xn.z - xc.z;
        float dd = d0*d0 + d1*d1 + d2v*d2v;
        _Float16 ddh = (_Float16)dd;
        h2 dd2 = {ddh, ddh};
        h2 cs2 = h2z;
        if (LYR == 0) { _Float16 ch = (_Float16)xc.w; cs2 = (h2){ch, ch}; }

        h2 sv = h2z;
#pragma unroll
        for (int k = 0; k < 4; ++k) {
            h2 gsk;
            if (LYR == 0) gsk = cs2 * P_pk[k];
            else gsk = u2h(k == 0 ? ga.x : (k == 1 ? ga.y : (k == 2 ? ga.z : ga.w)));
            h2 m = dd2 * w1e_pk[k] + gdn_pk[k] + gsk;
            m = __builtin_elementwise_max(m, h2z);
            if (HAS_NEXT) agg_pk[k] += m;
            sv = m * wv_pk[k] + sv;
        }
        float sval = (float)sv[0] + (float)sv[1];
        sval += __shfl_xor(sval, 1);       // combine halves (pair-uniform branch)
        av0 = __builtin_fmaf(d0, sval, av0);
        av1 = __builtin_fmaf(d1, sval, av1);
        av2 = __builtin_fmaf(d2v, sval, av2);

        e = e2; have = have2; xc = xc2; ga = ga2;
    }

    // av reduce across the 4 pairs (pair lanes already identical)
    av0 += __shfl_xor(av0, 2); av0 += __shfl_xor(av0, 4);
    av1 += __shfl_xor(av1, 2); av1 += __shfl_xor(av1, 4);
    av2 += __shfl_xor(av2, 2); av2 += __shfl_xor(av2, 4);

    if (HAS_NEXT) {
        if (o < 3) {
            float myav = (o == 0) ? av0 : ((o == 1) ? av1 : av2);
            vec[(size_t)g * 3 + o] += myav;    // vec pre-initialized to vs
        }

        // full agg for own half: packed reduce across pairs, then unpack + partner
        float agg[8], aggO[8];
#pragma unroll
        for (int k = 0; k < 4; ++k) {
            agg_pk[k] += u2h(__shfl_xor(h2u(agg_pk[k]), 2));
            agg_pk[k] += u2h(__shfl_xor(h2u(agg_pk[k]), 4));
            unsigned po = __shfl_xor(h2u(agg_pk[k]), 1);
            h2 v = agg_pk[k], vo = u2h(po);
            agg[2*k]   = (float)v[0];  agg[2*k+1]  = (float)v[1];
            aggO[2*k]  = (float)vo[0]; aggO[2*k+1] = (float)vo[1];
        }
        const int j0 = hb;          // W2 row base for own-half agg
        const int j1 = 8 - hb;      // row base for partner-half agg

        // hn: own 2 features (columns o*2, o*2+1), fp16 in hbuf
        float hq0, hq1;
        if (LYR == 0) {
            hq0 = c0 * s_rwe[o * 2];
            hq1 = c0 * s_rwe[o * 2 + 1];
        } else {
            f16unpack2(hbuf[(size_t)g * 8 + o], hq0, hq1);
        }

        float a0 = s_b2[o * 2], a1 = s_b2[o * 2 + 1];
#pragma unroll
        for (int k = 0; k < 8; ++k) {
            a0 = __builtin_fmaf(agg[k],  s_W2[(j0 + k) * 16 + o * 2],     a0);
            a1 = __builtin_fmaf(agg[k],  s_W2[(j0 + k) * 16 + o * 2 + 1], a1);
            a0 = __builtin_fmaf(aggO[k], s_W2[(j1 + k) * 16 + o * 2],     a0);
            a1 = __builtin_fmaf(aggO[k], s_W2[(j1 + k) * 16 + o * 2 + 1], a1);
        }
        hq0 += fmaxf(a0, 0.0f);
        hq1 += fmaxf(a1, 0.0f);

        // exchange across the octet -> full hnew[16]
        const int lane = tid & 63;
        const int lbase = lane & ~7;
        float hfull[16];
#pragma unroll
        for (int sq = 0; sq < 8; ++sq) {
            hfull[sq * 2]     = __shfl(hq0, lbase + sq, 64);
            hfull[sq * 2 + 1] = __shfl(hq1, lbase + sq, 64);
        }

        // next-layer projections, own 2 columns
        float gs0 = 0.0f, gs1 = 0.0f;
        float gd0 = s_b1n[o * 2], gd1 = s_b1n[o * 2 + 1];
#pragma unroll
        for (int jj = 0; jj < 16; ++jj) {
            float hj = hfull[jj];
            gs0 = __builtin_fmaf(hj, s_W1sn[jj * 16 + o * 2],     gs0);
            gs1 = __builtin_fmaf(hj, s_W1sn[jj * 16 + o * 2 + 1], gs1);
            gd0 = __builtin_fmaf(hj, s_W1dn[jj * 16 + o * 2],     gd0);
            gd1 = __builtin_fmaf(hj, s_W1dn[jj * 16 + o * 2 + 1], gd1);
        }

        hbuf[(size_t)g * 8 + o] = f16pack2(hq0, hq1);
        // gs pair -> rec_out uint index g*12 + o (record = 12 uints, gs = 0..7)
        ((unsigned*)rec_out)[(size_t)g * 12 + o] = f16pack2(gs0, gs1);
        ((unsigned*)gd)[(size_t)g * 8 + o]       = f16pack2(gd0, gd1);
    } else {
        // final layer: out[b*N+node] += w_t * (vec + av + x)
        if (o < 3) {
            float myav = (o == 0) ? av0 : ((o == 1) ? av1 : av2);
            float xno  = (o == 0) ? xn.x : ((o == 1) ? xn.y : xn.z);
            float prev = vec[(size_t)g * 3 + o];
            int b = tb & 7;
            atomicAdd(&outp[((size_t)b * N_ + node) * 3 + o],
                      wsm * (prev + myav + xno));
        }
    }
}

// ---------------------------------------------------------------------------
extern "C" void kernel_launch(void* const* d_in, const int* in_sizes, int n_in,
                              void* d_out, int out_size, void* d_ws, size_t ws_size,
                              hipStream_t stream) {
    const float* xs       = (const float*)d_in[0];
    const float* vs       = (const float*)d_in[1];
    const float* charges  = (const float*)d_in[2];
    const int*   edge_src = (const int*)d_in[3];
    const int*   edge_dst = (const int*)d_in[4];
    const float* theta    = (const float*)d_in[5];
    const float* W_embed  = (const float*)d_in[6];
    const float* W1       = (const float*)d_in[7];
    const float* b1       = (const float*)d_in[8];
    const float* W2       = (const float*)d_in[9];
    const float* b2       = (const float*)d_in[10];
    const float* Wv       = (const float*)d_in[11];
    float* out = (float*)d_out;

    // workspace layout (256B aligned)
    char* w = (char*)d_ws;
    size_t off = 0;
    auto take = [&](size_t bytes) {
        size_t o = off;
        off = (off + bytes + 255) & ~(size_t)255;
        return o;
    };
    int*            cursor = (int*)(w + take((size_t)N_ * 4));
    unsigned short* csr_b  = (unsigned short*)(w + take((size_t)N_ * CAP * 2));
    float4*         rec0   = (float4*)(w + take((size_t)TBN * 48));
    float4*         rec1   = (float4*)(w + take((size_t)TBN * 48));
    unsigned*       hbuf   = (unsigned*)(w + take((size_t)TBN * 32));   // fp16 x16
    unsigned*       gd     = (unsigned*)(w + take((size_t)TBN * 32));
    float*          vec    = (float*)(w + take((size_t)TBN * 3 * 4));
    (void)ws_size;

    hipMemsetAsync(cursor, 0, (size_t)N_ * 4, stream);
    hipMemsetAsync(out, 0, (size_t)out_size * 4, stream);
    k_build<<<EB + IB, 256, 0, stream>>>(edge_src, edge_dst, cursor, csr_b,
                                         xs, vs, charges, rec0, rec1, vec);

    // layer 0 reads rec0 (xyz+charge), writes rec1.gs + gd + h; layer 1 reads
    // rec1, writes rec0.gs + gd + h; layer 2 reads rec0, accumulates out
    k_layer<0, true ><<<LB, 256, 0, stream>>>(rec0, rec1, W_embed, W1, b1, W2, b2, Wv,
                                              theta, cursor, csr_b, hbuf, gd, vec, out);
    k_layer<1, true ><<<LB, 256, 0, stream>>>(rec1, rec0, W_embed, W1, b1, W2, b2, Wv,
                                              theta, cursor, csr_b, hbuf, gd, vec, out);
    k_layer<2, false><<<LB, 256, 0, stream>>>(rec0, nullptr, W_embed, W1, b1, W2, b2, Wv,
                                              theta, cursor, csr_b, hbuf, gd, vec, out);
}